// Round 3
// baseline (281.298 us; speedup 1.0000x reference)
//
#include <hip/hip_runtime.h>

#define NCOL 17
#define WAVE 64
#define BLK  256
#define WPB  (BLK / WAVE)            // 4 waves per block
#define WTILE (WAVE * NCOL)          // 1088 floats = 4352 B per wave-tile (16B aligned)
#define WVEC4 (WTILE / 4)            // 272 float4
#define MAX_GRID 2048                // 256 CU x 8 resident blocks/CU

__global__ __launch_bounds__(BLK) void bsp_prime_kernel(
    const float* __restrict__ x, float* __restrict__ out, int n) {
    // 16 * C(15,k)  (the /scale = *16 folded into the coefficients)
    const float C15x16[16] = {16.f,    240.f,   1680.f,  7280.f,
                              21840.f, 48048.f, 80080.f, 102960.f,
                              102960.f, 80080.f, 48048.f, 21840.f,
                              7280.f,  1680.f,  240.f,   16.f};

    // Wave-PRIVATE tiles: lane l only ever writes row l of its own wave's
    // slice, and the wave drains only its own slice. No inter-wave
    // communication -> NO __syncthreads -> no vmcnt(0) store-drain before
    // barriers; global stores stay in flight across iterations.
    __shared__ float tile[WPB][WTILE];  // 17408 B -> 8 blocks/CU

    const int t = threadIdx.x;
    const int w = t >> 6;   // wave within block
    const int l = t & 63;   // lane
    float* __restrict__ wt = tile[w];

    const int ntiles = (n + WAVE - 1) / WAVE;        // 62500 at N=4M
    const long long total = (long long)n * NCOL;
    const int wid0 = blockIdx.x * WPB + w;
    const int wstride = gridDim.x * WPB;

    for (int tb = wid0; tb < ntiles; tb += wstride) {
        const int i = tb * WAVE + l;
        float y = (i < n) ? x[i] : 0.5f;
        // Reference's 0*log(0)=NaN -> zeroed rows at exact endpoints
        const bool edge = (y <= 0.0f) || (y >= 1.0f);
        const float omy = 1.0f - y;

        float yp[NCOL], op[NCOL];
        yp[0] = 1.0f;
        op[0] = 1.0f;
#pragma unroll
        for (int k = 1; k < NCOL; ++k) {
            yp[k] = yp[k - 1] * y;
            op[k] = op[k - 1] * omy;
        }

        // sec(m) == first(m+1):  f[m] = 16*C(15,m-1)*y^(m-1)*(1-y)^(16-m)
        // v[m] = f[m] - f[m+1],  f[0] = f[17] = 0
        float f[NCOL + 1];
        f[0] = 0.0f;
        f[NCOL] = 0.0f;
#pragma unroll
        for (int m = 1; m <= 16; ++m) {
            f[m] = C15x16[m - 1] * yp[m - 1] * op[16 - m];
        }

        // LDS transpose write: stride-17 floats -> 2-way bank alias (free).
        // Intra-wave ds ordering via compiler lgkmcnt; no barrier needed.
#pragma unroll
        for (int m = 0; m < NCOL; ++m) {
            wt[l * NCOL + m] = edge ? 0.0f : (f[m] - f[m + 1]);
        }

        // Coalesced drain of this wave's contiguous 4352-B span of out.
        const long long base = (long long)tb * WTILE;
        if (base + WTILE <= total) {
            const float4* __restrict__ s4 = (const float4*)wt;
            float4* __restrict__ o4 = (float4*)(out + base);
#pragma unroll
            for (int k = 0; k < 4; ++k) {
                o4[k * WAVE + l] = s4[k * WAVE + l];
            }
            if (l < WVEC4 - 4 * WAVE) {  // 16 leftover float4
                o4[4 * WAVE + l] = s4[4 * WAVE + l];
            }
        } else {
            // Generic tail (unused at N=4M since 4M % 64 == 0)
            for (int k = 0; k < NCOL; ++k) {
                long long idx = base + (long long)k * WAVE + l;
                if (idx < total) out[idx] = wt[k * WAVE + l];
            }
        }
    }
}

extern "C" void kernel_launch(void* const* d_in, const int* in_sizes, int n_in,
                              void* d_out, int out_size, void* d_ws, size_t ws_size,
                              hipStream_t stream) {
    const float* x = (const float*)d_in[0];
    float* out = (float*)d_out;
    const int n = in_sizes[0];  // 4,000,000 points
    const int nblocks = (n + BLK - 1) / BLK;
    const int grid = nblocks < MAX_GRID ? nblocks : MAX_GRID;
    bsp_prime_kernel<<<grid, BLK, 0, stream>>>(x, out, n);
}

// Round 4
// 279.955 us; speedup vs baseline: 1.0048x; 1.0048x over previous
//
#include <hip/hip_runtime.h>

#define NCOL 17
#define WAVE 64
#define BLK  256
#define WPB  (BLK / WAVE)            // 4 waves per block
#define WTILE (WAVE * NCOL)          // 1088 floats = 4352 B per wave-tile (16B aligned)
#define WVEC4 (WTILE / 4)            // 272 float4
#define MAX_GRID 2048                // 256 CU x 8 resident blocks/CU

typedef float f32x4 __attribute__((ext_vector_type(4)));

__global__ __launch_bounds__(BLK) void bsp_prime_kernel(
    const float* __restrict__ x, float* __restrict__ out, int n) {
    // 16 * C(15,k)  (the /scale = *16 folded into the coefficients)
    const float C15x16[16] = {16.f,    240.f,   1680.f,  7280.f,
                              21840.f, 48048.f, 80080.f, 102960.f,
                              102960.f, 80080.f, 48048.f, 21840.f,
                              7280.f,  1680.f,  240.f,   16.f};

    // Wave-private tiles; no __syncthreads anywhere (intra-wave LDS ordering
    // is handled by compiler-inserted lgkmcnt).
    __shared__ float tile[WPB][WTILE];  // 17408 B -> 8 blocks/CU

    const int t = threadIdx.x;
    const int w = t >> 6;   // wave within block
    const int l = t & 63;   // lane
    float* __restrict__ wt = tile[w];

    const int ntiles = (n + WAVE - 1) / WAVE;        // 62500 at N=4M
    const long long total = (long long)n * NCOL;
    const int wid0 = blockIdx.x * WPB + w;
    const int wstride = gridDim.x * WPB;

    for (int tb = wid0; tb < ntiles; tb += wstride) {
        const int i = tb * WAVE + l;
        float y = (i < n) ? x[i] : 0.5f;
        // Reference's 0*log(0)=NaN -> zeroed rows at exact endpoints
        const bool edge = (y <= 0.0f) || (y >= 1.0f);
        const float omy = 1.0f - y;

        float yp[NCOL], op[NCOL];
        yp[0] = 1.0f;
        op[0] = 1.0f;
#pragma unroll
        for (int k = 1; k < NCOL; ++k) {
            yp[k] = yp[k - 1] * y;
            op[k] = op[k - 1] * omy;
        }

        // sec(m) == first(m+1):  f[m] = 16*C(15,m-1)*y^(m-1)*(1-y)^(16-m)
        // v[m] = f[m] - f[m+1],  f[0] = f[17] = 0
        float f[NCOL + 1];
        f[0] = 0.0f;
        f[NCOL] = 0.0f;
#pragma unroll
        for (int m = 1; m <= 16; ++m) {
            f[m] = C15x16[m - 1] * yp[m - 1] * op[16 - m];
        }

        // LDS transpose write: stride-17 floats -> 2-way bank alias (free).
#pragma unroll
        for (int m = 0; m < NCOL; ++m) {
            wt[l * NCOL + m] = edge ? 0.0f : (f[m] - f[m + 1]);
        }

        // Coalesced drain, NON-TEMPORAL: out is write-once/never-reread.
        // nt skips L2 write-allocate (no read-for-ownership fetch) — the
        // poison fill sustains 6.2 TB/s with FETCH_SIZE==0 on this path.
        const long long base = (long long)tb * WTILE;
        if (base + WTILE <= total) {
            const f32x4* __restrict__ s4 = (const f32x4*)wt;
            f32x4* __restrict__ o4 = (f32x4*)(out + base);
#pragma unroll
            for (int k = 0; k < 4; ++k) {
                __builtin_nontemporal_store(s4[k * WAVE + l], &o4[k * WAVE + l]);
            }
            if (l < WVEC4 - 4 * WAVE) {  // 16 leftover float4
                __builtin_nontemporal_store(s4[4 * WAVE + l], &o4[4 * WAVE + l]);
            }
        } else {
            // Generic tail (unused at N=4M since 4M % 64 == 0)
            for (int k = 0; k < NCOL; ++k) {
                long long idx = base + (long long)k * WAVE + l;
                if (idx < total)
                    __builtin_nontemporal_store(wt[k * WAVE + l], &out[idx]);
            }
        }
    }
}

extern "C" void kernel_launch(void* const* d_in, const int* in_sizes, int n_in,
                              void* d_out, int out_size, void* d_ws, size_t ws_size,
                              hipStream_t stream) {
    const float* x = (const float*)d_in[0];
    float* out = (float*)d_out;
    const int n = in_sizes[0];  // 4,000,000 points
    const int nblocks = (n + BLK - 1) / BLK;
    const int grid = nblocks < MAX_GRID ? nblocks : MAX_GRID;
    bsp_prime_kernel<<<grid, BLK, 0, stream>>>(x, out, n);
}